// Round 11
// baseline (269.675 us; speedup 1.0000x reference)
//
#include <hip/hip_runtime.h>
#include <hip/hip_bf16.h>

// Problem: T=255, B=256, NIN=784, NOUT=40
// out layout: [spk_rec (255*256*40) | mem_rec (255*256*40)] fp32
#define T_STEPS 255
#define BATCH 256
#define NIN 784
#define NOUT 40
#define NPAD 48   // 3 MFMA N-tiles of 16 (cols 40..47 zero)
#define MROWS (T_STEPS * BATCH)          // 65280
#define TBN (T_STEPS * BATCH * NOUT)     // 2611200
#define BN_CH (BATCH * NOUT)             // 10240

#define BM 128    // 4 waves x 32 rows -> grid 510
#define BK 56     // 784 = 14 * 56
#define LDX 60    // fp32 X LDS row stride (dwords)
#define LDW 50    // fp64 W LDS row stride (doubles)
#define LDWC 60   // fp32 W LDS row stride (fallback kernel)

typedef double f64x4 __attribute__((ext_vector_type(4)));

// Build Wt[784][48] fp64: Wt[k][n] = (n<40) ? (double)W[n][k] : 0.
// Lives at head of spk output region (301 KB << 10.4 MB); scan overwrites it.
__global__ __launch_bounds__(256) void wtrans_kernel(
    const float* __restrict__ W, double* __restrict__ Wt) {
  int i = blockIdx.x * 256 + threadIdx.x;
  if (i < NIN * NPAD) {
    int k = i / NPAD, n = i % NPAD;
    Wt[i] = (n < NOUT) ? (double)W[n * NIN + k] : 0.0;
  }
}

// f64-MFMA GEMM with runtime fragment-layout probes. gfx950's
// v_mfma_f64_16x16x4_f64 lane maps are unverified; we resolve A/B maps
// (row-major vs k-major) and D orientation with 3 probe MFMAs, then a
// separate check kernel validates 64 outputs and arms the VALU fallback.
__global__ __launch_bounds__(256) void lif_gemm_mfma(
    const float* __restrict__ X, const double* __restrict__ Wt,
    float* __restrict__ cur) {
  alignas(16) __shared__ float xs[BM * LDX];   // 30.0 KB
  alignas(16) __shared__ double wl[BK * LDW];  // 21.9 KB ([k][n] fp64 pad)
  const int tid = threadIdx.x;
  const int m0 = blockIdx.x * BM;
  const int w = tid >> 6;        // wave 0..3 -> rows [w*32, w*32+32)
  const int l = tid & 63;
  const int wm = w * 32;

  // --- probe 1: resolve A map. a = lane id, B = all-ones ->
  // D[0][0] = sum of lane ids in A-row 0: row-major {0,16,32,48}=96,
  // k-major {0,1,2,3}=6. Lane0/reg0 is D[0][0] under both D orientations.
  f64x4 p = {0.0, 0.0, 0.0, 0.0};
  p = __builtin_amdgcn_mfma_f64_16x16x4f64((double)l, 1.0, p, 0, 0, 0);
  const bool aT = (__shfl(p[0], 0) < 50.0);  // k-major A?
  // --- probe 2: resolve B map symmetrically.
  p = f64x4{0.0, 0.0, 0.0, 0.0};
  p = __builtin_amdgcn_mfma_f64_16x16x4f64(1.0, (double)l, p, 0, 0, 0);
  const bool bT = (__shfl(p[0], 0) < 50.0);  // k-major B?

  const int am = aT ? (l >> 2) : (l & 15);
  const int ak = aT ? (l & 3) : (l >> 4);
  const int bk = bT ? (l & 3) : (l >> 4);
  const int bj = bT ? (l >> 2) : (l & 15);

  // --- probe 3: D orientation with resolved A/B. A[m][k]=m, B[k][j]=(j==0)
  // -> D[m][j] = 4m*(j==0). lane1/reg0: std layout D[0][1]=0, transposed
  // layout D[1][0]=4.
  p = f64x4{0.0, 0.0, 0.0, 0.0};
  p = __builtin_amdgcn_mfma_f64_16x16x4f64(
      (double)am, (bj == 0) ? 1.0 : 0.0, p, 0, 0, 0);
  const bool dT = (__shfl(p[0], 1) > 2.0);

  f64x4 acc[2][3];
#pragma unroll
  for (int s = 0; s < 2; ++s)
#pragma unroll
    for (int t = 0; t < 3; ++t) acc[s][t] = f64x4{0.0, 0.0, 0.0, 0.0};

  for (int k0 = 0; k0 < NIN; k0 += BK) {
    // stage X tile: 128 rows x 56 cols fp32 = 1792 float4 / 256 thr = 7 each
#pragma unroll
    for (int i = 0; i < 7; ++i) {
      unsigned id = tid + i * 256u;
      unsigned row = id / 14u;
      unsigned c4 = id % 14u;
      float4 v = *reinterpret_cast<const float4*>(
          X + (size_t)(m0 + row) * NIN + k0 + c4 * 4);
      *reinterpret_cast<float4*>(&xs[row * LDX + c4 * 4]) = v;
    }
    // stage W tile: contiguous Wt[k0..k0+56)[0..48) = 1344 double2
#pragma unroll
    for (int i = 0; i < 6; ++i) {
      unsigned id = tid + i * 256u;
      if (id < BK * (NPAD / 2)) {
        unsigned row = id / 24u;
        unsigned c2 = id % 24u;
        double2 v = *reinterpret_cast<const double2*>(
            Wt + (size_t)k0 * NPAD + row * NPAD + c2 * 2);
        *reinterpret_cast<double2*>(&wl[row * LDW + c2 * 2]) = v;
      }
    }
    __syncthreads();

#pragma unroll
    for (int kk = 0; kk < BK; kk += 4) {
      double a0 = (double)xs[(wm + am) * LDX + kk + ak];
      double a1 = (double)xs[(wm + 16 + am) * LDX + kk + ak];
      const double* wrow = &wl[(kk + bk) * LDW];
      double b0 = wrow[bj];
      double b1 = wrow[16 + bj];
      double b2 = wrow[32 + bj];
      acc[0][0] = __builtin_amdgcn_mfma_f64_16x16x4f64(a0, b0, acc[0][0], 0, 0, 0);
      acc[0][1] = __builtin_amdgcn_mfma_f64_16x16x4f64(a0, b1, acc[0][1], 0, 0, 0);
      acc[0][2] = __builtin_amdgcn_mfma_f64_16x16x4f64(a0, b2, acc[0][2], 0, 0, 0);
      acc[1][0] = __builtin_amdgcn_mfma_f64_16x16x4f64(a1, b0, acc[1][0], 0, 0, 0);
      acc[1][1] = __builtin_amdgcn_mfma_f64_16x16x4f64(a1, b1, acc[1][1], 0, 0, 0);
      acc[1][2] = __builtin_amdgcn_mfma_f64_16x16x4f64(a1, b2, acc[1][2], 0, 0, 0);
    }
    __syncthreads();
  }

  const int dlr = l & 15, dlg = l >> 4;
#pragma unroll
  for (int s = 0; s < 2; ++s) {
#pragma unroll
    for (int t = 0; t < 3; ++t) {
#pragma unroll
      for (int r = 0; r < 4; ++r) {
        int rin = dT ? dlr : (dlg * 4 + r);
        int cin = dT ? (dlg * 4 + r) : dlr;
        int col = t * 16 + cin;
        if (col < NOUT) {
          size_t grow = (size_t)m0 + wm + s * 16 + rin;
          cur[grow * NOUT + col] = (float)acc[s][t][r];
        }
      }
    }
  }
}

// One wave; 64 scattered (row,col) samples recomputed with fp64 VALU dots
// against the ORIGINAL X/W (independent of wtrans/MFMA). flag=1 -> fallback.
__global__ __launch_bounds__(64) void check_kernel(
    const float* __restrict__ X, const float* __restrict__ W,
    const float* __restrict__ cur, int* __restrict__ flag) {
  const int l = threadIdx.x;
  const int r = (l * 1021) % MROWS;
  const int c = (l * 7 + 3) % NOUT;
  double dot = 0.0;
  for (int k = 0; k < NIN; k += 4) {
    float4 xv = *reinterpret_cast<const float4*>(X + (size_t)r * NIN + k);
    float4 wv = *reinterpret_cast<const float4*>(W + (size_t)c * NIN + k);
    dot = fma((double)xv.x, (double)wv.x, dot);
    dot = fma((double)xv.y, (double)wv.y, dot);
    dot = fma((double)xv.z, (double)wv.z, dot);
    dot = fma((double)xv.w, (double)wv.w, dot);
  }
  float got = cur[(size_t)r * NOUT + c];
  int bad = (fabs((double)got - dot) > 1e-4) ? 1 : 0;
  unsigned long long anybad = __ballot(bad != 0);
  if (l == 0) *flag = (anybad != 0ull) ? 1 : 0;
}

// Fallback: the validated round-8 fp64-VALU GEMM, armed by flag.
// FMA chain per output element bit-identical to the validated kernels.
__global__ __launch_bounds__(256) void lif_gemm_full(
    const float* __restrict__ X, const float* __restrict__ W,
    float* __restrict__ cur, const int* __restrict__ flag) {
  if (*(volatile const int*)flag == 0) return;
  __shared__ float xs[BM * LDX];
  __shared__ float wl[NOUT * LDWC];
  const int tid = threadIdx.x;
  const int m0 = blockIdx.x * BM;
  const int w = tid >> 6;
  const int l = tid & 63;
  const int rl = l & 31;
  const int h = l >> 5;
  const int c0 = (w * 2 + h) * 5;

  double acc[4][5];
#pragma unroll
  for (int r = 0; r < 4; ++r)
#pragma unroll
    for (int c = 0; c < 5; ++c) acc[r][c] = 0.0;

  for (int k0 = 0; k0 < NIN; k0 += BK) {
#pragma unroll
    for (int i = 0; i < 7; ++i) {
      unsigned id = tid + i * 256u;
      unsigned row = id / 14u;
      unsigned c4 = id % 14u;
      float4 v = *reinterpret_cast<const float4*>(
          X + (size_t)(m0 + row) * NIN + k0 + c4 * 4);
      *reinterpret_cast<float4*>(&xs[row * LDX + c4 * 4]) = v;
    }
#pragma unroll
    for (int i = 0; i < 3; ++i) {
      unsigned id = tid + i * 256u;
      if (id < NOUT * 14u) {
        unsigned row = id / 14u;
        unsigned c4 = id % 14u;
        float4 v = *reinterpret_cast<const float4*>(
            W + (size_t)row * NIN + k0 + c4 * 4);
        *reinterpret_cast<float4*>(&wl[row * LDWC + c4 * 4]) = v;
      }
    }
    __syncthreads();

#pragma unroll
    for (int kk = 0; kk < BK; kk += 4) {
      double xd[4][4];
#pragma unroll
      for (int r = 0; r < 4; ++r) {
        float4 xv = *reinterpret_cast<const float4*>(
            &xs[(rl + 32 * r) * LDX + kk]);
        xd[r][0] = (double)xv.x; xd[r][1] = (double)xv.y;
        xd[r][2] = (double)xv.z; xd[r][3] = (double)xv.w;
      }
#pragma unroll
      for (int c = 0; c < 5; ++c) {
        float4 wv = *reinterpret_cast<const float4*>(
            &wl[(c0 + c) * LDWC + kk]);
        double wa = (double)wv.x, wb = (double)wv.y,
               wc = (double)wv.z, wd = (double)wv.w;
#pragma unroll
        for (int r = 0; r < 4; ++r) {
          acc[r][c] = fma(xd[r][0], wa, acc[r][c]);
          acc[r][c] = fma(xd[r][1], wb, acc[r][c]);
          acc[r][c] = fma(xd[r][2], wc, acc[r][c]);
          acc[r][c] = fma(xd[r][3], wd, acc[r][c]);
        }
      }
    }
    __syncthreads();
  }

#pragma unroll
  for (int r = 0; r < 4; ++r) {
    const size_t mrow = (size_t)m0 + rl + 32 * r;
#pragma unroll
    for (int c = 0; c < 5; ++c)
      cur[mrow * NOUT + c0 + c] = (float)acc[r][c];
  }
}

// One thread per (b, n) chain; 17 chunks of 15 t-steps with next-chunk
// prefetch. Per-step math identical to the validated scan (asm barrier
// blocks fma contraction, matching numpy's two roundings).
__global__ __launch_bounds__(64) void lif_scan_kernel(
    float* __restrict__ spk, float* __restrict__ curmem) {
  const int idx = blockIdx.x * 64 + threadIdx.x;  // 0..10239
  float mem = 0.f;
  float c[15];
#pragma unroll
  for (int i = 0; i < 15; ++i) c[i] = curmem[(size_t)i * BN_CH + idx];

  for (int ch = 0; ch < 17; ++ch) {
    const int t0 = ch * 15;
    float n[15];
    if (ch != 16) {
#pragma unroll
      for (int i = 0; i < 15; ++i)
        n[i] = curmem[(size_t)(t0 + 15 + i) * BN_CH + idx];
    }
    float m_[15], s_[15];
#pragma unroll
    for (int i = 0; i < 15; ++i) {
      float reset = (mem > 1.0f) ? 1.0f : 0.0f;
      float decay = 0.95f * mem;
      asm volatile("" : "+v"(decay));  // forbid fma contraction
      float summ = decay + c[i];
      float mnew = summ * (1.0f - reset);
      m_[i] = mnew;
      s_[i] = (mnew > 1.0f) ? 1.0f : 0.0f;
      mem = mnew;
    }
#pragma unroll
    for (int i = 0; i < 15; ++i) {
      curmem[(size_t)(t0 + i) * BN_CH + idx] = m_[i];
      spk[(size_t)(t0 + i) * BN_CH + idx] = s_[i];
    }
    if (ch != 16) {
#pragma unroll
      for (int i = 0; i < 15; ++i) c[i] = n[i];
    }
  }
}

extern "C" void kernel_launch(void* const* d_in, const int* in_sizes, int n_in,
                              void* d_out, int out_size, void* d_ws,
                              size_t ws_size, hipStream_t stream) {
  (void)in_sizes; (void)n_in; (void)out_size; (void)ws_size;
  const float* X = (const float*)d_in[0];
  const float* W = (const float*)d_in[1];
  float* out = (float*)d_out;
  float* spk = out;            // [255,256,40]
  float* memout = out + TBN;   // [255,256,40], used as cur scratch then mem
  double* Wt = (double*)out;   // 301 KB scratch at head of spk region
  int* flag = (int*)d_ws;

  wtrans_kernel<<<(NIN * NPAD + 255) / 256, 256, 0, stream>>>(W, Wt);
  lif_gemm_mfma<<<MROWS / BM, 256, 0, stream>>>(X, Wt, memout);
  check_kernel<<<1, 64, 0, stream>>>(X, W, memout, flag);
  lif_gemm_full<<<MROWS / BM, 256, 0, stream>>>(X, W, memout, flag);
  lif_scan_kernel<<<BN_CH / 64, 64, 0, stream>>>(spk, memout);
}

// Round 12
// 136.158 us; speedup vs baseline: 1.9806x; 1.9806x over previous
//
#include <hip/hip_runtime.h>
#include <hip/hip_bf16.h>

// Problem: T=255, B=256, NIN=784, NOUT=40
// out layout: [spk_rec (255*256*40) | mem_rec (255*256*40)] fp32
#define T_STEPS 255
#define BATCH 256
#define NIN 784
#define NOUT 40
#define MROWS (T_STEPS * BATCH)          // 65280
#define TBN (T_STEPS * BATCH * NOUT)     // 2611200
#define BN_CH (BATCH * NOUT)             // 10240

#define BM 128    // 4 rows/thread x 32 lane-rows -> grid 510
#define BK 56     // 784 = 14 * 56

// fp64-VALU GEMM, 4 rows x 5 cols per thread.
// X LDS tile is QUAD-MAJOR: xs[c4][row][4] so the fragment read for quad kk
// is 32 consecutive 16B chunks (lane rl -> byte rl*16) -> zero bank
// conflicts (R8's row-major read was a structural 4-way conflict: any 16B-
// aligned row stride puts 32 stride-separated lanes in 8 bank groups).
// W is staged as fp64 (cvt once at staging, not 20x per quad in the loop).
// FMA chain per output element is bit-identical to the validated round-2/8
// kernels (k ascending, quads of 4 sequential FMAs, exact f32->f64 cvts):
// cur is correctly-rounded fp32 -> spike decisions match the references.
__global__ __launch_bounds__(256) void lif_gemm_kernel(
    const float* __restrict__ X, const float* __restrict__ W,
    float* __restrict__ cur) {
  alignas(16) __shared__ float xs[14 * 128 * 4];   // 28672 B, [c4][row][4]
  alignas(16) __shared__ double wl[NOUT * BK];     // 17920 B, [col][56] fp64
  const int tid = threadIdx.x;
  const int m0 = blockIdx.x * BM;
  const int w = tid >> 6;        // wave 0..3
  const int l = tid & 63;
  const int rl = l & 31;         // row within 32-row band
  const int h = l >> 5;          // col-half 0/1
  const int c0 = (w * 2 + h) * 5;  // col base: 8 groups of 5 -> 40 cols

  double acc[4][5];
#pragma unroll
  for (int r = 0; r < 4; ++r)
#pragma unroll
    for (int c = 0; c < 5; ++c) acc[r][c] = 0.0;

  for (int k0 = 0; k0 < NIN; k0 += BK) {
    // stage X tile quad-major: 1792 float4 / 256 thr = 7 each
#pragma unroll
    for (int i = 0; i < 7; ++i) {
      unsigned id = tid + i * 256u;
      unsigned row = id / 14u;  // 14 float4 per row
      unsigned c4 = id % 14u;
      float4 v = *reinterpret_cast<const float4*>(
          X + (size_t)(m0 + row) * NIN + k0 + c4 * 4);
      *reinterpret_cast<float4*>(&xs[c4 * 512 + row * 4]) = v;
    }
    // stage W tile as fp64: 40 cols x 28 double2 = 1120 over 256 threads
#pragma unroll
    for (int i = 0; i < 5; ++i) {
      unsigned id = tid + i * 256u;
      if (id < NOUT * 28u) {
        unsigned col = id / 28u;
        unsigned c2 = id % 28u;
        float2 v = *reinterpret_cast<const float2*>(
            W + (size_t)col * NIN + k0 + c2 * 2);
        double2 d;
        d.x = (double)v.x;
        d.y = (double)v.y;
        *reinterpret_cast<double2*>(&wl[col * BK + c2 * 2]) = d;
      }
    }
    __syncthreads();

#pragma unroll
    for (int kk = 0; kk < BK; kk += 4) {
      double xd[4][4];
#pragma unroll
      for (int r = 0; r < 4; ++r) {
        float4 xv = *reinterpret_cast<const float4*>(
            &xs[(kk >> 2) * 512 + (rl + 32 * r) * 4]);
        xd[r][0] = (double)xv.x; xd[r][1] = (double)xv.y;
        xd[r][2] = (double)xv.z; xd[r][3] = (double)xv.w;
      }
#pragma unroll
      for (int c = 0; c < 5; ++c) {
        double2 w01 = *reinterpret_cast<const double2*>(&wl[(c0 + c) * BK + kk]);
        double2 w23 = *reinterpret_cast<const double2*>(&wl[(c0 + c) * BK + kk + 2]);
        const double wa = w01.x, wb = w01.y, wc = w23.x, wd = w23.y;
#pragma unroll
        for (int r = 0; r < 4; ++r) {
          acc[r][c] = fma(xd[r][0], wa, acc[r][c]);
          acc[r][c] = fma(xd[r][1], wb, acc[r][c]);
          acc[r][c] = fma(xd[r][2], wc, acc[r][c]);
          acc[r][c] = fma(xd[r][3], wd, acc[r][c]);
        }
      }
    }
    __syncthreads();
  }

#pragma unroll
  for (int r = 0; r < 4; ++r) {
    const size_t mrow = (size_t)m0 + rl + 32 * r;
#pragma unroll
    for (int c = 0; c < 5; ++c)
      cur[mrow * NOUT + c0 + c] = (float)acc[r][c];
  }
}

// One thread per (b, n) chain; 17 chunks of 15 t-steps, next chunk's cur
// loads prefetched before computing the current chunk (hides L2 latency).
// Per-step math identical to the validated scan (asm barrier blocks fma
// contraction of 0.95f*mem + cur, matching numpy's two roundings).
__global__ __launch_bounds__(64) void lif_scan_kernel(
    float* __restrict__ spk, float* __restrict__ curmem) {
  const int idx = blockIdx.x * 64 + threadIdx.x;  // 0..10239
  float mem = 0.f;
  float c[15];
#pragma unroll
  for (int i = 0; i < 15; ++i) c[i] = curmem[(size_t)i * BN_CH + idx];

  for (int ch = 0; ch < 17; ++ch) {
    const int t0 = ch * 15;
    float n[15];
    if (ch != 16) {
#pragma unroll
      for (int i = 0; i < 15; ++i)
        n[i] = curmem[(size_t)(t0 + 15 + i) * BN_CH + idx];
    }
    float m_[15], s_[15];
#pragma unroll
    for (int i = 0; i < 15; ++i) {
      float reset = (mem > 1.0f) ? 1.0f : 0.0f;
      float decay = 0.95f * mem;
      asm volatile("" : "+v"(decay));  // forbid fma contraction
      float summ = decay + c[i];
      float mnew = summ * (1.0f - reset);
      m_[i] = mnew;
      s_[i] = (mnew > 1.0f) ? 1.0f : 0.0f;
      mem = mnew;
    }
#pragma unroll
    for (int i = 0; i < 15; ++i) {
      curmem[(size_t)(t0 + i) * BN_CH + idx] = m_[i];
      spk[(size_t)(t0 + i) * BN_CH + idx] = s_[i];
    }
    if (ch != 16) {
#pragma unroll
      for (int i = 0; i < 15; ++i) c[i] = n[i];
    }
  }
}

extern "C" void kernel_launch(void* const* d_in, const int* in_sizes, int n_in,
                              void* d_out, int out_size, void* d_ws,
                              size_t ws_size, hipStream_t stream) {
  (void)in_sizes; (void)n_in; (void)out_size; (void)d_ws; (void)ws_size;
  const float* X = (const float*)d_in[0];
  const float* W = (const float*)d_in[1];
  float* out = (float*)d_out;
  float* spk = out;            // [255,256,40]
  float* memout = out + TBN;   // [255,256,40], used as cur scratch then mem

  lif_gemm_kernel<<<MROWS / BM, 256, 0, stream>>>(X, W, memout);
  lif_scan_kernel<<<BN_CH / 64, 64, 0, stream>>>(spk, memout);
}